// Round 1
// baseline (2880.458 us; speedup 1.0000x reference)
//
#include <hip/hip_runtime.h>
#include <math.h>
#include <float.h>

#define N_FR 32768
#define M_DIM 1024
#define D_DIM 512
#define K_CB 4096

// ---- d_out layout (floats) ----
// [0, N*M)                : out
// [N*M]                   : loss
// [N*M+1]                 : perplexity
// [N*M+2, N*M+2+N*K)      : encodings  (also used as scratch before final write)
static const long long OUT_ELEMS = (long long)N_FR * M_DIM;            // 33554432
static const long long LOSS_OFF  = OUT_ELEMS;
static const long long PPL_OFF   = OUT_ELEMS + 1;
static const long long ENC_OFF   = OUT_ELEMS + 2;                      // 33554434
static const long long Z_OFF     = ENC_OFF + 2;                        // 16B aligned
static const long long DC_OFF    = Z_OFF + (long long)N_FR * D_DIM;    // decoded codebook [K][M]
static const long long PV_OFF    = DC_OFF + (long long)K_CB * M_DIM;   // partial best val [4][N]
static const long long PI_OFF    = PV_OFF + 4LL * N_FR;                // partial best idx [4][N]

// ------------------------------------------------------------------
// Generic fp32 NT GEMM: C[i][j] = sum_k A[i*NK+k]*B[j*NK+k] + epilogue
// EPI==0: bias + BatchNorm (encoder).  EPI==1: bias only (decoded codebook).
// ------------------------------------------------------------------
template<int EPI>
__global__ __launch_bounds__(256)
void gemm_nt(const float* __restrict__ A, const float* __restrict__ B,
             float* __restrict__ C, int NI, int NJ, int NK,
             const float* __restrict__ bias,
             const float* __restrict__ gamma, const float* __restrict__ beta,
             const float* __restrict__ mean, const float* __restrict__ var)
{
    const int BK = 16;
    __shared__ float As[16][128];
    __shared__ float Bs[16][128];
    const int nbi = NI / 128;
    const int bi = blockIdx.x % nbi;
    const int bj = blockIdx.x / nbi;
    const int tid = threadIdx.x;
    const int tx = tid & 15, ty = tid >> 4;
    const int i0 = bi * 128, j0 = bj * 128;
    const int r0 = tid >> 2;             // 0..63
    const int kq = (tid & 3) * 4;        // 0,4,8,12

    float acc[8][8] = {};

    for (int k0 = 0; k0 < NK; k0 += BK) {
        __syncthreads();
        #pragma unroll
        for (int rr = 0; rr < 128; rr += 64) {
            float4 va = *(const float4*)&A[(long long)(i0 + r0 + rr) * NK + k0 + kq];
            As[kq + 0][r0 + rr] = va.x;
            As[kq + 1][r0 + rr] = va.y;
            As[kq + 2][r0 + rr] = va.z;
            As[kq + 3][r0 + rr] = va.w;
            float4 vb = *(const float4*)&B[(long long)(j0 + r0 + rr) * NK + k0 + kq];
            Bs[kq + 0][r0 + rr] = vb.x;
            Bs[kq + 1][r0 + rr] = vb.y;
            Bs[kq + 2][r0 + rr] = vb.z;
            Bs[kq + 3][r0 + rr] = vb.w;
        }
        __syncthreads();
        #pragma unroll
        for (int kk = 0; kk < BK; ++kk) {
            float a[8], b[8];
            #pragma unroll
            for (int i = 0; i < 8; ++i) a[i] = As[kk][ty * 8 + i];
            #pragma unroll
            for (int j = 0; j < 8; ++j) b[j] = Bs[kk][tx * 8 + j];
            #pragma unroll
            for (int i = 0; i < 8; ++i)
                #pragma unroll
                for (int j = 0; j < 8; ++j)
                    acc[i][j] = fmaf(a[i], b[j], acc[i][j]);
        }
    }

    // epilogue params for this thread's 8 columns
    float bv[8], g[8], bt[8], mn[8], rs[8];
    #pragma unroll
    for (int j = 0; j < 8; ++j) {
        int jj = j0 + tx * 8 + j;
        bv[j] = bias[jj];
        if (EPI == 0) {
            g[j]  = gamma[jj];
            bt[j] = beta[jj];
            mn[j] = mean[jj];
            rs[j] = (float)(1.0 / sqrt((double)var[jj] + 1e-5));
        }
    }
    #pragma unroll
    for (int i = 0; i < 8; ++i) {
        int ii = i0 + ty * 8 + i;
        float vals[8];
        #pragma unroll
        for (int j = 0; j < 8; ++j) {
            float v = acc[i][j] + bv[j];
            if (EPI == 0) v = (v - mn[j]) * rs[j] * g[j] + bt[j];
            vals[j] = v;
        }
        float4* cp = (float4*)&C[(long long)ii * NJ + j0 + tx * 8];
        cp[0] = make_float4(vals[0], vals[1], vals[2], vals[3]);
        cp[1] = make_float4(vals[4], vals[5], vals[6], vals[7]);
    }
}

// ------------------------------------------------------------------
// se[k] = sum_d codebook[k][d]^2
// ------------------------------------------------------------------
__global__ __launch_bounds__(256)
void se_k(const float* __restrict__ CB, float* __restrict__ se)
{
    int row  = blockIdx.x * 4 + (threadIdx.x >> 6);
    int lane = threadIdx.x & 63;
    const float4* p = (const float4*)(CB + (long long)row * D_DIM + lane * 8);
    float4 a = p[0], b = p[1];
    float s = a.x*a.x + a.y*a.y + a.z*a.z + a.w*a.w
            + b.x*b.x + b.y*b.y + b.z*b.z + b.w*b.w;
    #pragma unroll
    for (int off = 32; off; off >>= 1) s += __shfl_xor(s, off);
    if (lane == 0) se[row] = s;
}

// ------------------------------------------------------------------
// Distance + argmin over a 1024-code chunk per block (4 chunks x 256 row-tiles).
// dist ordering key: se[k] - 2 * z.e_k   (||z||^2 is row-constant -> dropped)
// ------------------------------------------------------------------
__global__ __launch_bounds__(256)
void argmin_k(const float* __restrict__ Z, const float* __restrict__ CB,
              const float* __restrict__ se,
              float* __restrict__ pval, int* __restrict__ pidx)
{
    const int BK = 16, CHUNK = 1024;
    __shared__ float Zs[16][128];
    __shared__ float Cs[16][128];
    __shared__ float bval[128];
    __shared__ int   bidx[128];
    const int brow = blockIdx.x & 255;
    const int bch  = blockIdx.x >> 8;
    const int row0 = brow * 128;
    const int tid = threadIdx.x;
    const int tx = tid & 15, ty = tid >> 4;
    const int r0 = tid >> 2;
    const int kq = (tid & 3) * 4;

    if (tid < 128) { bval[tid] = FLT_MAX; bidx[tid] = 0x7fffffff; }

    for (int j0 = 0; j0 < CHUNK; j0 += 128) {
        const int code0 = bch * CHUNK + j0;
        float acc[8][8] = {};
        for (int d0 = 0; d0 < D_DIM; d0 += BK) {
            __syncthreads();
            #pragma unroll
            for (int rr = 0; rr < 128; rr += 64) {
                float4 vz = *(const float4*)&Z[(long long)(row0 + r0 + rr) * D_DIM + d0 + kq];
                Zs[kq + 0][r0 + rr] = vz.x;
                Zs[kq + 1][r0 + rr] = vz.y;
                Zs[kq + 2][r0 + rr] = vz.z;
                Zs[kq + 3][r0 + rr] = vz.w;
                float4 vc = *(const float4*)&CB[(long long)(code0 + r0 + rr) * D_DIM + d0 + kq];
                Cs[kq + 0][r0 + rr] = vc.x;
                Cs[kq + 1][r0 + rr] = vc.y;
                Cs[kq + 2][r0 + rr] = vc.z;
                Cs[kq + 3][r0 + rr] = vc.w;
            }
            __syncthreads();
            #pragma unroll
            for (int kk = 0; kk < BK; ++kk) {
                float a[8], b[8];
                #pragma unroll
                for (int i = 0; i < 8; ++i) a[i] = Zs[kk][ty * 8 + i];
                #pragma unroll
                for (int j = 0; j < 8; ++j) b[j] = Cs[kk][tx * 8 + j];
                #pragma unroll
                for (int i = 0; i < 8; ++i)
                    #pragma unroll
                    for (int j = 0; j < 8; ++j)
                        acc[i][j] = fmaf(a[i], b[j], acc[i][j]);
            }
        }
        // per-thread 8 codes, ascending index; tie -> lower index
        float se8[8];
        #pragma unroll
        for (int j = 0; j < 8; ++j) se8[j] = se[code0 + tx * 8 + j];
        #pragma unroll
        for (int r = 0; r < 8; ++r) {
            float best = se8[0] - 2.0f * acc[r][0];
            int   bj   = code0 + tx * 8;
            #pragma unroll
            for (int j = 1; j < 8; ++j) {
                float d = se8[j] - 2.0f * acc[r][j];
                if (d < best) { best = d; bj = code0 + tx * 8 + j; }
            }
            // reduce across the 16 tx lanes (within one wave)
            #pragma unroll
            for (int off = 1; off < 16; off <<= 1) {
                float ov = __shfl_xor(best, off);
                int   oi = __shfl_xor(bj, off);
                if (ov < best || (ov == best && oi < bj)) { best = ov; bj = oi; }
            }
            if (tx == 0) {
                int row = ty * 8 + r;
                if (best < bval[row]) { bval[row] = best; bidx[row] = bj; }
            }
        }
    }
    __syncthreads();
    if (tid < 128) {
        pval[(long long)bch * N_FR + row0 + tid] = bval[tid];
        pidx[(long long)bch * N_FR + row0 + tid] = bidx[tid];
    }
}

// ------------------------------------------------------------------
// Merge 4 chunk-partials -> final index; histogram counts.
// ------------------------------------------------------------------
__global__ __launch_bounds__(256)
void merge_k(const float* __restrict__ pval, const int* __restrict__ pidx,
             int* __restrict__ fidx, int* __restrict__ counts)
{
    int n = blockIdx.x * 256 + threadIdx.x;
    float best = pval[n];
    int   bi   = pidx[n];
    #pragma unroll
    for (int c = 1; c < 4; ++c) {
        float v = pval[(long long)c * N_FR + n];
        int   i = pidx[(long long)c * N_FR + n];
        if (v < best) { best = v; bi = i; }   // chunks ascend in index; tie keeps lower
    }
    fidx[n] = bi;
    atomicAdd(&counts[bi], 1);
}

// ------------------------------------------------------------------
// loss accumulation: sum over n,d of (cb[idx[n]][d] - z[n][d])^2
// ------------------------------------------------------------------
__global__ __launch_bounds__(256)
void loss_k(const float* __restrict__ Z, const float* __restrict__ CB,
            const int* __restrict__ fidx, double* __restrict__ dsum)
{
    int row  = blockIdx.x * 4 + (threadIdx.x >> 6);
    int lane = threadIdx.x & 63;
    int id = fidx[row];
    const float4* zp = (const float4*)(Z  + (long long)row * D_DIM + lane * 8);
    const float4* cp = (const float4*)(CB + (long long)id  * D_DIM + lane * 8);
    float4 z0 = zp[0], z1 = zp[1], c0 = cp[0], c1 = cp[1];
    float s = 0.f, d;
    d = c0.x - z0.x; s += d * d;  d = c0.y - z0.y; s += d * d;
    d = c0.z - z0.z; s += d * d;  d = c0.w - z0.w; s += d * d;
    d = c1.x - z1.x; s += d * d;  d = c1.y - z1.y; s += d * d;
    d = c1.z - z1.z; s += d * d;  d = c1.w - z1.w; s += d * d;
    #pragma unroll
    for (int off = 32; off; off >>= 1) s += __shfl_xor(s, off);
    if (lane == 0) atomicAdd(dsum, (double)s);
}

// ------------------------------------------------------------------
// out[n][:] = dec_cb[idx[n]][:]
// ------------------------------------------------------------------
__global__ __launch_bounds__(256)
void gather_k(const float* __restrict__ DC, const int* __restrict__ fidx,
              float* __restrict__ outp)
{
    int n = blockIdx.x;
    int id = fidx[n];
    float4 v = ((const float4*)(DC + (long long)id * M_DIM))[threadIdx.x];
    ((float4*)(outp + (long long)n * M_DIM))[threadIdx.x] = v;
}

// ------------------------------------------------------------------
// encodings[n][idx[n]] = 1  (region pre-zeroed by memset)
// ------------------------------------------------------------------
__global__ __launch_bounds__(256)
void scatter_k(const int* __restrict__ fidx, float* __restrict__ enc)
{
    int n = blockIdx.x * 256 + threadIdx.x;
    enc[(long long)n * K_CB + fidx[n]] = 1.0f;
}

// ------------------------------------------------------------------
// loss + perplexity scalars
// ------------------------------------------------------------------
__global__ __launch_bounds__(256)
void fin_k(const int* __restrict__ counts, const double* __restrict__ dsum,
           float* __restrict__ scal)
{
    __shared__ double sh[4];
    int tid = threadIdx.x;
    double s = 0.0;
    for (int k = tid; k < K_CB; k += 256) {
        double p = (double)counts[k] / (double)N_FR;
        s += p * log(p + 1e-10);
    }
    #pragma unroll
    for (int off = 32; off; off >>= 1) s += __shfl_xor(s, off);
    if ((tid & 63) == 0) sh[tid >> 6] = s;
    __syncthreads();
    if (tid == 0) {
        double tot = sh[0] + sh[1] + sh[2] + sh[3];
        scal[0] = (float)(0.25 * (*dsum) / ((double)N_FR * (double)D_DIM));
        scal[1] = (float)exp(-tot);
    }
}

extern "C" void kernel_launch(void* const* d_in, const int* in_sizes, int n_in,
                              void* d_out, int out_size, void* d_ws, size_t ws_size,
                              hipStream_t stream)
{
    (void)in_sizes; (void)n_in; (void)out_size; (void)ws_size;
    const float* x        = (const float*)d_in[0];
    const float* enc_w    = (const float*)d_in[1];
    const float* enc_b    = (const float*)d_in[2];
    const float* bn_gamma = (const float*)d_in[3];
    const float* bn_beta  = (const float*)d_in[4];
    const float* bn_mean  = (const float*)d_in[5];
    const float* bn_var   = (const float*)d_in[6];
    const float* cb       = (const float*)d_in[7];
    const float* dec_w    = (const float*)d_in[8];
    const float* dec_b    = (const float*)d_in[9];

    float* outp = (float*)d_out;
    float* z    = outp + Z_OFF;
    float* dc   = outp + DC_OFF;
    float* pval = outp + PV_OFF;
    int*   pidx = (int*)(outp + PI_OFF);

    char*   wsb    = (char*)d_ws;
    int*    fidx   = (int*)wsb;                    // N ints
    int*    counts = (int*)(wsb + 131072);         // K ints
    float*  se     = (float*)(wsb + 147456);       // K floats
    double* dsum   = (double*)(wsb + 163840);      // 1 double

    // zero counts + se + dsum (se rewritten below anyway)
    hipMemsetAsync(counts, 0, 32776, stream);

    // encoder GEMM + BN -> z
    gemm_nt<0><<<dim3((N_FR / 128) * (D_DIM / 128)), 256, 0, stream>>>(
        x, enc_w, z, N_FR, D_DIM, M_DIM, enc_b, bn_gamma, bn_beta, bn_mean, bn_var);
    // codebook row norms
    se_k<<<dim3(K_CB / 4), 256, 0, stream>>>(cb, se);
    // decoded codebook: dec_cb = codebook @ dec_w.T + dec_b
    gemm_nt<1><<<dim3((K_CB / 128) * (M_DIM / 128)), 256, 0, stream>>>(
        cb, dec_w, dc, K_CB, M_DIM, D_DIM, dec_b, nullptr, nullptr, nullptr, nullptr);
    // distances + chunk-partial argmin
    argmin_k<<<dim3(1024), 256, 0, stream>>>(z, cb, se, pval, pidx);
    // merge partials, histogram
    merge_k<<<dim3(N_FR / 256), 256, 0, stream>>>(pval, pidx, fidx, counts);
    // commitment loss accumulation (needs z, before enc-region memset)
    loss_k<<<dim3(N_FR / 4), 256, 0, stream>>>(z, cb, fidx, dsum);
    // decoder output gather (needs dec_cb, before enc-region memset)
    gather_k<<<dim3(N_FR), 256, 0, stream>>>(dc, fidx, outp);
    // scalars
    fin_k<<<dim3(1), 256, 0, stream>>>(counts, dsum, outp + LOSS_OFF);
    // zero the encodings region (wipes z/dc/pval/pidx scratch), then scatter ones
    hipMemsetAsync(outp + ENC_OFF, 0, (size_t)N_FR * K_CB * sizeof(float), stream);
    scatter_k<<<dim3(N_FR / 256), 256, 0, stream>>>(fidx, outp + ENC_OFF);
}

// Round 2
// 1453.525 us; speedup vs baseline: 1.9817x; 1.9817x over previous
//
#include <hip/hip_runtime.h>
#include <math.h>
#include <float.h>

#define N_FR 32768
#define M_DIM 1024
#define D_DIM 512
#define K_CB 4096

// ---- d_out layout (floats) ----
// [0, N*M) out | [N*M] loss | [N*M+1] ppl | [N*M+2, +N*K) encodings (scratch until final)
static const long long OUT_ELEMS = (long long)N_FR * M_DIM;
static const long long LOSS_OFF  = OUT_ELEMS;
static const long long ENC_OFF   = OUT_ELEMS + 2;
static const long long Z_OFF     = ENC_OFF + 2;                         // fp32 z [N][D]
static const long long DC_OFF    = Z_OFF  + (long long)N_FR * D_DIM;    // fp32 dec_cb [K][M]
static const long long XH_OFF    = DC_OFF + (long long)K_CB * M_DIM;    // packed halves below
static const long long XL_OFF    = XH_OFF + (long long)N_FR * M_DIM / 2;
static const long long WH_OFF    = XL_OFF + (long long)N_FR * M_DIM / 2;
static const long long WL_OFF    = WH_OFF + (long long)D_DIM * M_DIM / 2;
static const long long CH_OFF    = WL_OFF + (long long)D_DIM * M_DIM / 2;
static const long long CL_OFF    = CH_OFF + (long long)K_CB * D_DIM / 2;
static const long long ZH_OFF    = CL_OFF + (long long)K_CB * D_DIM / 2;
static const long long ZL_OFF    = ZH_OFF + (long long)N_FR * D_DIM / 2;

typedef __attribute__((ext_vector_type(8))) short bf16x8;
typedef __attribute__((ext_vector_type(8))) unsigned short u16x8;
typedef __attribute__((ext_vector_type(4))) float f32x4;

__device__ __forceinline__ unsigned short f2bf(float f) {
    unsigned u = __float_as_uint(f);
    return (unsigned short)((u + 0x7fffu + ((u >> 16) & 1u)) >> 16);
}
__device__ __forceinline__ float bf2f(unsigned short h) {
    return __uint_as_float(((unsigned)h) << 16);
}
__device__ __forceinline__ void gl_lds16(const unsigned short* g, unsigned short* l) {
    __builtin_amdgcn_global_load_lds(
        (const __attribute__((address_space(1))) unsigned int*)g,
        (__attribute__((address_space(3))) unsigned int*)l,
        16, 0, 0);
}

// ------------------------------------------------------------------
// fp32 [R][C] -> hi/lo bf16, fragment-blocked:
// flat16 = b*512 + lane*8 + j,  b = (r>>4)*(C/32) + (c>>5),
// lane = (r&15) + 16*((c>>3)&3), j = c&7.
// One wave per 16x32 block; writes are contiguous 1KB per wave.
// ------------------------------------------------------------------
__global__ __launch_bounds__(256)
void conv_split(const float* __restrict__ in, unsigned short* __restrict__ hi,
                unsigned short* __restrict__ lo, int C, int KC)
{
    int w = blockIdx.x * 4 + (threadIdx.x >> 6);
    int lane = threadIdx.x & 63;
    int bn = w / KC, ck = w % KC;
    int r = bn * 16 + (lane & 15);
    int c = ck * 32 + (lane >> 4) * 8;
    const float4* p = (const float4*)&in[(size_t)r * C + c];
    float4 v0 = p[0], v1 = p[1];
    float f[8] = {v0.x, v0.y, v0.z, v0.w, v1.x, v1.y, v1.z, v1.w};
    u16x8 hv, lv;
    #pragma unroll
    for (int j = 0; j < 8; ++j) {
        unsigned short h = f2bf(f[j]);
        hv[j] = h;
        lv[j] = f2bf(f[j] - bf2f(h));
    }
    size_t o = (size_t)w * 512 + lane * 8;
    *(u16x8*)&hi[o] = hv;
    *(u16x8*)&lo[o] = lv;
}

// ------------------------------------------------------------------
// Encoder: z = BN(x @ enc_w.T + b). bf16 3-pass split MFMA.
// Block: 128 rows x 128 cols, 4 waves (2x2), wave 64x64 (4x4 frags).
// ------------------------------------------------------------------
__global__ __launch_bounds__(256)
void gemm_enc(const unsigned short* __restrict__ xh, const unsigned short* __restrict__ xl,
              const unsigned short* __restrict__ wh, const unsigned short* __restrict__ wl,
              const float* __restrict__ bias, const float* __restrict__ gamma,
              const float* __restrict__ beta, const float* __restrict__ mean,
              const float* __restrict__ var, float* __restrict__ Z)
{
    __shared__ unsigned short lds[16384];   // 32 KB: xh[0:8K) xl[8K:16K) wh[16K:24K) wl[24K:32K)
    const int tid = threadIdx.x, wid = tid >> 6, lane = tid & 63;
    const int wr = wid >> 1, wc = wid & 1;
    const int bi = blockIdx.x & 255, bj = blockIdx.x >> 8;

    f32x4 acc[4][4];
    #pragma unroll
    for (int i = 0; i < 4; ++i)
        #pragma unroll
        for (int j = 0; j < 4; ++j) acc[i][j] = (f32x4){0.f, 0.f, 0.f, 0.f};

    for (int ks = 0; ks < 32; ++ks) {
        __syncthreads();
        #pragma unroll
        for (int q = 0; q < 8; ++q) {
            int id = wid * 8 + q;
            int arr = id >> 3, rb = id & 7;
            const unsigned short* base = arr == 0 ? xh : arr == 1 ? xl : arr == 2 ? wh : wl;
            size_t b = (size_t)((arr < 2 ? bi : bj) * 8 + rb) * 32 + ks;
            gl_lds16(base + b * 512 + lane * 8, (unsigned short*)((char*)lds + id * 1024));
        }
        __syncthreads();
        bf16x8 ah[4], al[4], bh[4], bl[4];
        #pragma unroll
        for (int i = 0; i < 4; ++i) {
            ah[i] = *(const bf16x8*)((const char*)lds + (4 * wr + i) * 1024 + lane * 16);
            al[i] = *(const bf16x8*)((const char*)lds + 8192 + (4 * wr + i) * 1024 + lane * 16);
        }
        #pragma unroll
        for (int j = 0; j < 4; ++j) {
            bh[j] = *(const bf16x8*)((const char*)lds + 16384 + (4 * wc + j) * 1024 + lane * 16);
            bl[j] = *(const bf16x8*)((const char*)lds + 24576 + (4 * wc + j) * 1024 + lane * 16);
        }
        #pragma unroll
        for (int i = 0; i < 4; ++i)
            #pragma unroll
            for (int j = 0; j < 4; ++j) {
                acc[i][j] = __builtin_amdgcn_mfma_f32_16x16x32_bf16(ah[i], bh[j], acc[i][j], 0, 0, 0);
                acc[i][j] = __builtin_amdgcn_mfma_f32_16x16x32_bf16(ah[i], bl[j], acc[i][j], 0, 0, 0);
                acc[i][j] = __builtin_amdgcn_mfma_f32_16x16x32_bf16(al[i], bh[j], acc[i][j], 0, 0, 0);
            }
    }
    #pragma unroll
    for (int j = 0; j < 4; ++j) {
        int col = bj * 128 + wc * 64 + j * 16 + (lane & 15);
        float bvv = bias[col], g = gamma[col], bt = beta[col], mn = mean[col];
        float rs = (float)(1.0 / sqrt((double)var[col] + 1e-5));
        #pragma unroll
        for (int i = 0; i < 4; ++i)
            #pragma unroll
            for (int r = 0; r < 4; ++r) {
                int row = bi * 128 + wr * 64 + i * 16 + (lane >> 4) * 4 + r;
                float v = acc[i][j][r] + bvv;
                Z[(size_t)row * D_DIM + col] = (v - mn) * rs * g + bt;
            }
    }
}

// ------------------------------------------------------------------
// Fused distance + argmin, bf16 3-pass MFMA.
// Block: 64 rows x all 4096 codes (32 chunks of 128). 4 waves (2x2),
// wave 32 rows x 64 codes (2x4 frags). key = se[k] - 2*z.e_k.
// ------------------------------------------------------------------
__global__ __launch_bounds__(256)
void argmin_mfma(const unsigned short* __restrict__ zh, const unsigned short* __restrict__ zl,
                 const unsigned short* __restrict__ ch, const unsigned short* __restrict__ cl,
                 const float* __restrict__ se, int* __restrict__ fidx, int* __restrict__ counts)
{
    __shared__ unsigned short lds[12288];   // 24 KB: zh[0:4K) zl[4K:8K) ch[8K:16K) cl[16K:24K)
    __shared__ float sv[64][2];
    __shared__ int   si[64][2];
    const int tid = threadIdx.x, wid = tid >> 6, lane = tid & 63;
    const int wr = wid >> 1, wc = wid & 1;
    const int row0 = blockIdx.x * 64;

    float bv[8]; int bi[8];
    #pragma unroll
    for (int s = 0; s < 8; ++s) { bv[s] = FLT_MAX; bi[s] = 0x7fffffff; }

    for (int cc = 0; cc < 32; ++cc) {
        f32x4 acc[2][4];
        #pragma unroll
        for (int i = 0; i < 2; ++i)
            #pragma unroll
            for (int j = 0; j < 4; ++j) acc[i][j] = (f32x4){0.f, 0.f, 0.f, 0.f};

        for (int ks = 0; ks < 16; ++ks) {
            __syncthreads();
            #pragma unroll
            for (int q = 0; q < 6; ++q) {
                int id = wid * 6 + q;
                const unsigned short* src; int loff;
                if (id < 8) {
                    int a = id >> 2, rb = id & 3;
                    size_t b = (size_t)((row0 >> 4) + rb) * 16 + ks;
                    src = (a ? zl : zh) + b * 512 + lane * 8;
                    loff = id * 1024;
                } else {
                    int a = (id - 8) >> 3, cb2 = (id - 8) & 7;
                    size_t b = (size_t)(cc * 8 + cb2) * 16 + ks;
                    src = (a ? cl : ch) + b * 512 + lane * 8;
                    loff = 8192 + (id - 8) * 1024;
                }
                gl_lds16(src, (unsigned short*)((char*)lds + loff));
            }
            __syncthreads();
            bf16x8 ah[2], al[2], bh[4], bl[4];
            #pragma unroll
            for (int i = 0; i < 2; ++i) {
                ah[i] = *(const bf16x8*)((const char*)lds + (2 * wr + i) * 1024 + lane * 16);
                al[i] = *(const bf16x8*)((const char*)lds + 4096 + (2 * wr + i) * 1024 + lane * 16);
            }
            #pragma unroll
            for (int j = 0; j < 4; ++j) {
                bh[j] = *(const bf16x8*)((const char*)lds + 8192  + (4 * wc + j) * 1024 + lane * 16);
                bl[j] = *(const bf16x8*)((const char*)lds + 16384 + (4 * wc + j) * 1024 + lane * 16);
            }
            #pragma unroll
            for (int i = 0; i < 2; ++i)
                #pragma unroll
                for (int j = 0; j < 4; ++j) {
                    acc[i][j] = __builtin_amdgcn_mfma_f32_16x16x32_bf16(ah[i], bh[j], acc[i][j], 0, 0, 0);
                    acc[i][j] = __builtin_amdgcn_mfma_f32_16x16x32_bf16(ah[i], bl[j], acc[i][j], 0, 0, 0);
                    acc[i][j] = __builtin_amdgcn_mfma_f32_16x16x32_bf16(al[i], bh[j], acc[i][j], 0, 0, 0);
                }
        }
        // fused argmin update (codes strictly ascending over cc, j -> tie keeps lower)
        #pragma unroll
        for (int j = 0; j < 4; ++j) {
            int code = cc * 128 + wc * 64 + j * 16 + (lane & 15);
            float sev = se[code];
            #pragma unroll
            for (int i = 0; i < 2; ++i)
                #pragma unroll
                for (int r = 0; r < 4; ++r) {
                    float key = sev - 2.0f * acc[i][j][r];
                    int s = i * 4 + r;
                    if (key < bv[s]) { bv[s] = key; bi[s] = code; }
                }
        }
    }
    // reduce across the 16 code-lanes (tie -> lower index)
    #pragma unroll
    for (int s = 0; s < 8; ++s) {
        #pragma unroll
        for (int off = 1; off < 16; off <<= 1) {
            float ov = __shfl_xor(bv[s], off);
            int   oi = __shfl_xor(bi[s], off);
            if (ov < bv[s] || (ov == bv[s] && oi < bi[s])) { bv[s] = ov; bi[s] = oi; }
        }
    }
    if ((lane & 15) == 0) {
        #pragma unroll
        for (int i = 0; i < 2; ++i)
            #pragma unroll
            for (int r = 0; r < 4; ++r) {
                int row = wr * 32 + i * 16 + (lane >> 4) * 4 + r;
                sv[row][wc] = bv[i * 4 + r];
                si[row][wc] = bi[i * 4 + r];
            }
    }
    __syncthreads();
    if (tid < 64) {
        float v0 = sv[tid][0], v1 = sv[tid][1];
        int   i0 = si[tid][0], i1 = si[tid][1];
        int best = (v1 < v0 || (v1 == v0 && i1 < i0)) ? i1 : i0;
        fidx[row0 + tid] = best;
        atomicAdd(&counts[best], 1);
    }
}

// ------------------------------------------------------------------
// fp32 NT GEMM, bias epilogue (decoded codebook only)
// ------------------------------------------------------------------
__global__ __launch_bounds__(256)
void gemm_nt_bias(const float* __restrict__ A, const float* __restrict__ B,
                  float* __restrict__ C, int NI, int NJ, int NK,
                  const float* __restrict__ bias)
{
    const int BK = 16;
    __shared__ float As[16][128];
    __shared__ float Bs[16][128];
    const int nbi = NI / 128;
    const int bi = blockIdx.x % nbi;
    const int bj = blockIdx.x / nbi;
    const int tid = threadIdx.x;
    const int tx = tid & 15, ty = tid >> 4;
    const int i0 = bi * 128, j0 = bj * 128;
    const int r0 = tid >> 2;
    const int kq = (tid & 3) * 4;

    float acc[8][8] = {};
    for (int k0 = 0; k0 < NK; k0 += BK) {
        __syncthreads();
        #pragma unroll
        for (int rr = 0; rr < 128; rr += 64) {
            float4 va = *(const float4*)&A[(long long)(i0 + r0 + rr) * NK + k0 + kq];
            As[kq + 0][r0 + rr] = va.x; As[kq + 1][r0 + rr] = va.y;
            As[kq + 2][r0 + rr] = va.z; As[kq + 3][r0 + rr] = va.w;
            float4 vb = *(const float4*)&B[(long long)(j0 + r0 + rr) * NK + k0 + kq];
            Bs[kq + 0][r0 + rr] = vb.x; Bs[kq + 1][r0 + rr] = vb.y;
            Bs[kq + 2][r0 + rr] = vb.z; Bs[kq + 3][r0 + rr] = vb.w;
        }
        __syncthreads();
        #pragma unroll
        for (int kk = 0; kk < BK; ++kk) {
            float a[8], b[8];
            #pragma unroll
            for (int i = 0; i < 8; ++i) a[i] = As[kk][ty * 8 + i];
            #pragma unroll
            for (int j = 0; j < 8; ++j) b[j] = Bs[kk][tx * 8 + j];
            #pragma unroll
            for (int i = 0; i < 8; ++i)
                #pragma unroll
                for (int j = 0; j < 8; ++j)
                    acc[i][j] = fmaf(a[i], b[j], acc[i][j]);
        }
    }
    float bv[8];
    #pragma unroll
    for (int j = 0; j < 8; ++j) bv[j] = bias[j0 + tx * 8 + j];
    #pragma unroll
    for (int i = 0; i < 8; ++i) {
        int ii = i0 + ty * 8 + i;
        float4* cp = (float4*)&C[(long long)ii * NJ + j0 + tx * 8];
        cp[0] = make_float4(acc[i][0] + bv[0], acc[i][1] + bv[1], acc[i][2] + bv[2], acc[i][3] + bv[3]);
        cp[1] = make_float4(acc[i][4] + bv[4], acc[i][5] + bv[5], acc[i][6] + bv[6], acc[i][7] + bv[7]);
    }
}

__global__ __launch_bounds__(256)
void se_k(const float* __restrict__ CB, float* __restrict__ se)
{
    int row  = blockIdx.x * 4 + (threadIdx.x >> 6);
    int lane = threadIdx.x & 63;
    const float4* p = (const float4*)(CB + (long long)row * D_DIM + lane * 8);
    float4 a = p[0], b = p[1];
    float s = a.x*a.x + a.y*a.y + a.z*a.z + a.w*a.w
            + b.x*b.x + b.y*b.y + b.z*b.z + b.w*b.w;
    #pragma unroll
    for (int off = 32; off; off >>= 1) s += __shfl_xor(s, off);
    if (lane == 0) se[row] = s;
}

__global__ __launch_bounds__(256)
void loss_k(const float* __restrict__ Z, const float* __restrict__ CB,
            const int* __restrict__ fidx, double* __restrict__ dsum)
{
    int row  = blockIdx.x * 4 + (threadIdx.x >> 6);
    int lane = threadIdx.x & 63;
    int id = fidx[row];
    const float4* zp = (const float4*)(Z  + (long long)row * D_DIM + lane * 8);
    const float4* cp = (const float4*)(CB + (long long)id  * D_DIM + lane * 8);
    float4 z0 = zp[0], z1 = zp[1], c0 = cp[0], c1 = cp[1];
    float s = 0.f, d;
    d = c0.x - z0.x; s += d * d;  d = c0.y - z0.y; s += d * d;
    d = c0.z - z0.z; s += d * d;  d = c0.w - z0.w; s += d * d;
    d = c1.x - z1.x; s += d * d;  d = c1.y - z1.y; s += d * d;
    d = c1.z - z1.z; s += d * d;  d = c1.w - z1.w; s += d * d;
    #pragma unroll
    for (int off = 32; off; off >>= 1) s += __shfl_xor(s, off);
    if (lane == 0) atomicAdd(dsum, (double)s);
}

__global__ __launch_bounds__(256)
void gather_k(const float* __restrict__ DC, const int* __restrict__ fidx,
              float* __restrict__ outp)
{
    int n = blockIdx.x;
    int id = fidx[n];
    float4 v = ((const float4*)(DC + (long long)id * M_DIM))[threadIdx.x];
    ((float4*)(outp + (long long)n * M_DIM))[threadIdx.x] = v;
}

__global__ __launch_bounds__(256)
void scatter_k(const int* __restrict__ fidx, float* __restrict__ enc)
{
    int n = blockIdx.x * 256 + threadIdx.x;
    enc[(long long)n * K_CB + fidx[n]] = 1.0f;
}

__global__ __launch_bounds__(256)
void fin_k(const int* __restrict__ counts, const double* __restrict__ dsum,
           float* __restrict__ scal)
{
    __shared__ double sh[4];
    int tid = threadIdx.x;
    double s = 0.0;
    for (int k = tid; k < K_CB; k += 256) {
        double p = (double)counts[k] / (double)N_FR;
        s += p * log(p + 1e-10);
    }
    #pragma unroll
    for (int off = 32; off; off >>= 1) s += __shfl_xor(s, off);
    if ((tid & 63) == 0) sh[tid >> 6] = s;
    __syncthreads();
    if (tid == 0) {
        double tot = sh[0] + sh[1] + sh[2] + sh[3];
        scal[0] = (float)(0.25 * (*dsum) / ((double)N_FR * (double)D_DIM));
        scal[1] = (float)exp(-tot);
    }
}

extern "C" void kernel_launch(void* const* d_in, const int* in_sizes, int n_in,
                              void* d_out, int out_size, void* d_ws, size_t ws_size,
                              hipStream_t stream)
{
    (void)in_sizes; (void)n_in; (void)out_size; (void)ws_size;
    const float* x        = (const float*)d_in[0];
    const float* enc_w    = (const float*)d_in[1];
    const float* enc_b    = (const float*)d_in[2];
    const float* bn_gamma = (const float*)d_in[3];
    const float* bn_beta  = (const float*)d_in[4];
    const float* bn_mean  = (const float*)d_in[5];
    const float* bn_var   = (const float*)d_in[6];
    const float* cb       = (const float*)d_in[7];
    const float* dec_w    = (const float*)d_in[8];
    const float* dec_b    = (const float*)d_in[9];

    float* outp = (float*)d_out;
    float* z    = outp + Z_OFF;
    float* dc   = outp + DC_OFF;
    unsigned short* xh  = (unsigned short*)(outp + XH_OFF);
    unsigned short* xl  = (unsigned short*)(outp + XL_OFF);
    unsigned short* whp = (unsigned short*)(outp + WH_OFF);
    unsigned short* wlp = (unsigned short*)(outp + WL_OFF);
    unsigned short* chp = (unsigned short*)(outp + CH_OFF);
    unsigned short* clp = (unsigned short*)(outp + CL_OFF);
    unsigned short* zhp = (unsigned short*)(outp + ZH_OFF);
    unsigned short* zlp = (unsigned short*)(outp + ZL_OFF);

    char*   wsb    = (char*)d_ws;
    int*    fidx   = (int*)wsb;                    // N ints
    int*    counts = (int*)(wsb + 131072);         // K ints
    float*  se     = (float*)(wsb + 147456);       // K floats
    double* dsum   = (double*)(wsb + 163840);      // 1 double

    hipMemsetAsync(counts, 0, 32776, stream);      // counts + se + dsum

    // split inputs into packed bf16 hi/lo
    conv_split<<<dim3(16384), 256, 0, stream>>>(x, xh, xl, M_DIM, M_DIM / 32);
    conv_split<<<dim3(256),   256, 0, stream>>>(enc_w, whp, wlp, M_DIM, M_DIM / 32);
    conv_split<<<dim3(1024),  256, 0, stream>>>(cb, chp, clp, D_DIM, D_DIM / 32);
    se_k<<<dim3(K_CB / 4), 256, 0, stream>>>(cb, se);

    // encoder (MFMA, 3-pass bf16) -> z fp32
    gemm_enc<<<dim3(1024), 256, 0, stream>>>(xh, xl, whp, wlp,
        enc_b, bn_gamma, bn_beta, bn_mean, bn_var, z);
    // split z
    conv_split<<<dim3(8192), 256, 0, stream>>>(z, zhp, zlp, D_DIM, D_DIM / 32);

    // decoded codebook (fp32): dec_cb = codebook @ dec_w.T + dec_b
    gemm_nt_bias<<<dim3((K_CB / 128) * (M_DIM / 128)), 256, 0, stream>>>(
        cb, dec_w, dc, K_CB, M_DIM, D_DIM, dec_b);

    // fused distances + argmin + histogram
    argmin_mfma<<<dim3(512), 256, 0, stream>>>(zhp, zlp, chp, clp, se, fidx, counts);

    loss_k<<<dim3(N_FR / 4), 256, 0, stream>>>(z, cb, fidx, dsum);
    gather_k<<<dim3(N_FR), 256, 0, stream>>>(dc, fidx, outp);
    fin_k<<<dim3(1), 256, 0, stream>>>(counts, dsum, outp + LOSS_OFF);

    hipMemsetAsync(outp + ENC_OFF, 0, (size_t)N_FR * K_CB * sizeof(float), stream);
    scatter_k<<<dim3(N_FR / 256), 256, 0, stream>>>(fidx, outp + ENC_OFF);
}

// Round 3
// 1212.267 us; speedup vs baseline: 2.3761x; 1.1990x over previous
//
#include <hip/hip_runtime.h>
#include <math.h>
#include <float.h>

#define N_FR 32768
#define M_DIM 1024
#define D_DIM 512
#define K_CB 4096

// ---- d_out layout (floats) ----
// [0, N*M) out | [N*M] loss | [N*M+1] ppl | [N*M+2, +N*K) encodings (scratch until final)
static const long long OUT_ELEMS = (long long)N_FR * M_DIM;
static const long long LOSS_OFF  = OUT_ELEMS;
static const long long ENC_OFF   = OUT_ELEMS + 2;
static const long long Z_OFF     = ENC_OFF + 2;                         // fp32 z [N][D]
static const long long DC_OFF    = Z_OFF  + (long long)N_FR * D_DIM;    // fp32 dec_cb [K][M]
static const long long XH_OFF    = DC_OFF + (long long)K_CB * M_DIM;    // packed halves below
static const long long XL_OFF    = XH_OFF + (long long)N_FR * M_DIM / 2;
static const long long WH_OFF    = XL_OFF + (long long)N_FR * M_DIM / 2;
static const long long WL_OFF    = WH_OFF + (long long)D_DIM * M_DIM / 2;
static const long long CH_OFF    = WL_OFF + (long long)D_DIM * M_DIM / 2;
static const long long CL_OFF    = CH_OFF + (long long)K_CB * D_DIM / 2;
static const long long ZH_OFF    = CL_OFF + (long long)K_CB * D_DIM / 2;
static const long long ZL_OFF    = ZH_OFF + (long long)N_FR * D_DIM / 2;
static const long long PV_OFF    = ZL_OFF + (long long)N_FR * D_DIM / 2; // partial best val [4][N]
static const long long PI_OFF    = PV_OFF + 4LL * N_FR;                  // partial best idx [4][N]

typedef __attribute__((ext_vector_type(8))) short bf16x8;
typedef __attribute__((ext_vector_type(8))) unsigned short u16x8;
typedef __attribute__((ext_vector_type(4))) float f32x4;

__device__ __forceinline__ unsigned short f2bf(float f) {
    unsigned u = __float_as_uint(f);
    return (unsigned short)((u + 0x7fffu + ((u >> 16) & 1u)) >> 16);
}
__device__ __forceinline__ float bf2f(unsigned short h) {
    return __uint_as_float(((unsigned)h) << 16);
}
__device__ __forceinline__ void gl_lds16(const unsigned short* g, unsigned short* l) {
    __builtin_amdgcn_global_load_lds(
        (const __attribute__((address_space(1))) unsigned int*)g,
        (__attribute__((address_space(3))) unsigned int*)l,
        16, 0, 0);
}

// ------------------------------------------------------------------
// fp32 [R][C] -> hi/lo bf16, fragment-blocked:
// flat16 = b*512 + lane*8 + j,  b = (r>>4)*(C/32) + (c>>5),
// lane = (r&15) + 16*((c>>3)&3), j = c&7.
// ------------------------------------------------------------------
__global__ __launch_bounds__(256)
void conv_split(const float* __restrict__ in, unsigned short* __restrict__ hi,
                unsigned short* __restrict__ lo, int C, int KC)
{
    int w = blockIdx.x * 4 + (threadIdx.x >> 6);
    int lane = threadIdx.x & 63;
    int bn = w / KC, ck = w % KC;
    int r = bn * 16 + (lane & 15);
    int c = ck * 32 + (lane >> 4) * 8;
    const float4* p = (const float4*)&in[(size_t)r * C + c];
    float4 v0 = p[0], v1 = p[1];
    float f[8] = {v0.x, v0.y, v0.z, v0.w, v1.x, v1.y, v1.z, v1.w};
    u16x8 hv, lv;
    #pragma unroll
    for (int j = 0; j < 8; ++j) {
        unsigned short h = f2bf(f[j]);
        hv[j] = h;
        lv[j] = f2bf(f[j] - bf2f(h));
    }
    size_t o = (size_t)w * 512 + lane * 8;
    *(u16x8*)&hi[o] = hv;
    *(u16x8*)&lo[o] = lv;
}

// ------------------------------------------------------------------
// Encoder: z = BN(x @ enc_w.T + b). bf16 3-pass split MFMA.
// ------------------------------------------------------------------
__global__ __launch_bounds__(256)
void gemm_enc(const unsigned short* __restrict__ xh, const unsigned short* __restrict__ xl,
              const unsigned short* __restrict__ wh, const unsigned short* __restrict__ wl,
              const float* __restrict__ bias, const float* __restrict__ gamma,
              const float* __restrict__ beta, const float* __restrict__ mean,
              const float* __restrict__ var, float* __restrict__ Z)
{
    __shared__ unsigned short lds[16384];
    const int tid = threadIdx.x, wid = tid >> 6, lane = tid & 63;
    const int wr = wid >> 1, wc = wid & 1;
    const int bi = blockIdx.x & 255, bj = blockIdx.x >> 8;

    f32x4 acc[4][4];
    #pragma unroll
    for (int i = 0; i < 4; ++i)
        #pragma unroll
        for (int j = 0; j < 4; ++j) acc[i][j] = (f32x4){0.f, 0.f, 0.f, 0.f};

    for (int ks = 0; ks < 32; ++ks) {
        __syncthreads();
        #pragma unroll
        for (int q = 0; q < 8; ++q) {
            int id = wid * 8 + q;
            int arr = id >> 3, rb = id & 7;
            const unsigned short* base = arr == 0 ? xh : arr == 1 ? xl : arr == 2 ? wh : wl;
            size_t b = (size_t)((arr < 2 ? bi : bj) * 8 + rb) * 32 + ks;
            gl_lds16(base + b * 512 + lane * 8, (unsigned short*)((char*)lds + id * 1024));
        }
        __syncthreads();
        bf16x8 ah[4], al[4], bh[4], bl[4];
        #pragma unroll
        for (int i = 0; i < 4; ++i) {
            ah[i] = *(const bf16x8*)((const char*)lds + (4 * wr + i) * 1024 + lane * 16);
            al[i] = *(const bf16x8*)((const char*)lds + 8192 + (4 * wr + i) * 1024 + lane * 16);
        }
        #pragma unroll
        for (int j = 0; j < 4; ++j) {
            bh[j] = *(const bf16x8*)((const char*)lds + 16384 + (4 * wc + j) * 1024 + lane * 16);
            bl[j] = *(const bf16x8*)((const char*)lds + 24576 + (4 * wc + j) * 1024 + lane * 16);
        }
        #pragma unroll
        for (int i = 0; i < 4; ++i)
            #pragma unroll
            for (int j = 0; j < 4; ++j) {
                acc[i][j] = __builtin_amdgcn_mfma_f32_16x16x32_bf16(ah[i], bh[j], acc[i][j], 0, 0, 0);
                acc[i][j] = __builtin_amdgcn_mfma_f32_16x16x32_bf16(ah[i], bl[j], acc[i][j], 0, 0, 0);
                acc[i][j] = __builtin_amdgcn_mfma_f32_16x16x32_bf16(al[i], bh[j], acc[i][j], 0, 0, 0);
            }
    }
    #pragma unroll
    for (int j = 0; j < 4; ++j) {
        int col = bj * 128 + wc * 64 + j * 16 + (lane & 15);
        float bvv = bias[col], g = gamma[col], bt = beta[col], mn = mean[col];
        float rs = (float)(1.0 / sqrt((double)var[col] + 1e-5));
        #pragma unroll
        for (int i = 0; i < 4; ++i)
            #pragma unroll
            for (int r = 0; r < 4; ++r) {
                int row = bi * 128 + wr * 64 + i * 16 + (lane >> 4) * 4 + r;
                float v = acc[i][j][r] + bvv;
                Z[(size_t)row * D_DIM + col] = (v - mn) * rs * g + bt;
            }
    }
}

// ------------------------------------------------------------------
// Fused distance + argmin v3. Grid 1024 = 256 row-tiles x 4 code-groups.
// Block: 128 rows x 1024 codes (4 chunks of 256). 4 waves (2x2),
// wave 64 rows x 128 codes (4x8 frags of 16x16x32, 3-pass split).
// Per ks: 24 ds_read_b128 (~288cy) vs 96 MFMA (~466cy) -> MFMA-bound.
// key = se[k] - 2*z.e_k ; tie -> lower index everywhere.
// ------------------------------------------------------------------
__global__ __launch_bounds__(256, 2)
void argmin_mfma(const unsigned short* __restrict__ zh, const unsigned short* __restrict__ zl,
                 const unsigned short* __restrict__ ch, const unsigned short* __restrict__ cl,
                 const float* __restrict__ se,
                 float* __restrict__ pval, int* __restrict__ pidx)
{
    __shared__ unsigned short lds[24576];   // 48KB: zh[0:8K) zl[8:16K) ch[16:32K) cl[32:48K) bytes
    __shared__ float sv[128][2];
    __shared__ int   si[128][2];
    const int tid = threadIdx.x, wid = tid >> 6, lane = tid & 63;
    const int wr = wid >> 1, wc = wid & 1;
    const int row0 = (int)(blockIdx.x >> 2) * 128;
    const int grp  = (int)(blockIdx.x & 3);

    float bv[16];
    int   bi[16];
    #pragma unroll
    for (int s = 0; s < 16; ++s) { bv[s] = FLT_MAX; bi[s] = 0x7fffffff; }

    for (int cc = 0; cc < 4; ++cc) {
        const int code0 = grp * 1024 + cc * 256;
        f32x4 acc[4][8];
        #pragma unroll
        for (int i = 0; i < 4; ++i)
            #pragma unroll
            for (int j = 0; j < 8; ++j) acc[i][j] = (f32x4){0.f, 0.f, 0.f, 0.f};

        for (int ks = 0; ks < 16; ++ks) {
            __syncthreads();
            // stage 48 x 1KB fragment-blocks: ids 0-7 zh, 8-15 zl, 16-31 ch, 32-47 cl
            #pragma unroll
            for (int q = 0; q < 12; ++q) {
                int id = wid * 12 + q;
                const unsigned short* src;
                if (id < 16) {
                    int a = id >> 3, rb = id & 7;
                    src = (a ? zl : zh) + ((size_t)((row0 >> 4) + rb) * 16 + ks) * 512 + lane * 8;
                } else {
                    int id2 = id - 16;
                    int a = id2 >> 4, cb2 = id2 & 15;
                    src = (a ? cl : ch) + ((size_t)((code0 >> 4) + cb2) * 16 + ks) * 512 + lane * 8;
                }
                gl_lds16(src, lds + id * 512);
            }
            __syncthreads();
            bf16x8 ah[4], al[4];
            #pragma unroll
            for (int i = 0; i < 4; ++i) {
                ah[i] = *(const bf16x8*)(lds + (wr * 4 + i) * 512 + lane * 8);
                al[i] = *(const bf16x8*)(lds + 4096 + (wr * 4 + i) * 512 + lane * 8);
            }
            #pragma unroll
            for (int j = 0; j < 8; ++j) {
                bf16x8 bhj = *(const bf16x8*)(lds + 8192  + (wc * 8 + j) * 512 + lane * 8);
                bf16x8 blj = *(const bf16x8*)(lds + 16384 + (wc * 8 + j) * 512 + lane * 8);
                #pragma unroll
                for (int i = 0; i < 4; ++i) {
                    acc[i][j] = __builtin_amdgcn_mfma_f32_16x16x32_bf16(ah[i], bhj, acc[i][j], 0, 0, 0);
                    acc[i][j] = __builtin_amdgcn_mfma_f32_16x16x32_bf16(ah[i], blj, acc[i][j], 0, 0, 0);
                    acc[i][j] = __builtin_amdgcn_mfma_f32_16x16x32_bf16(al[i], bhj, acc[i][j], 0, 0, 0);
                }
            }
        }
        // fold chunk into running per-lane best (codes strictly ascending)
        #pragma unroll
        for (int j = 0; j < 8; ++j) {
            int code = code0 + wc * 128 + j * 16 + (lane & 15);
            float sev = se[code];
            #pragma unroll
            for (int i = 0; i < 4; ++i)
                #pragma unroll
                for (int r = 0; r < 4; ++r) {
                    float key = sev - 2.0f * acc[i][j][r];
                    int s = i * 4 + r;
                    if (key < bv[s]) { bv[s] = key; bi[s] = code; }
                }
        }
    }
    // butterfly across the 16 code-lanes (tie -> lower index)
    #pragma unroll
    for (int s = 0; s < 16; ++s) {
        #pragma unroll
        for (int off = 1; off < 16; off <<= 1) {
            float ov = __shfl_xor(bv[s], off);
            int   oi = __shfl_xor(bi[s], off);
            if (ov < bv[s] || (ov == bv[s] && oi < bi[s])) { bv[s] = ov; bi[s] = oi; }
        }
    }
    if ((lane & 15) == 0) {
        #pragma unroll
        for (int i = 0; i < 4; ++i)
            #pragma unroll
            for (int r = 0; r < 4; ++r) {
                int row = wr * 64 + i * 16 + (lane >> 4) * 4 + r;
                sv[row][wc] = bv[i * 4 + r];
                si[row][wc] = bi[i * 4 + r];
            }
    }
    __syncthreads();
    if (tid < 128) {
        float v0 = sv[tid][0], v1 = sv[tid][1];
        int   i0 = si[tid][0], i1 = si[tid][1];
        float bvv = v0; int bii = i0;
        if (v1 < v0 || (v1 == v0 && i1 < i0)) { bvv = v1; bii = i1; }
        pval[(size_t)grp * N_FR + row0 + tid] = bvv;
        pidx[(size_t)grp * N_FR + row0 + tid] = bii;
    }
}

// ------------------------------------------------------------------
// Merge 4 code-group partials -> final index; histogram counts.
// ------------------------------------------------------------------
__global__ __launch_bounds__(256)
void merge_k(const float* __restrict__ pval, const int* __restrict__ pidx,
             int* __restrict__ fidx, int* __restrict__ counts)
{
    int n = blockIdx.x * 256 + threadIdx.x;
    float best = pval[n];
    int   bi   = pidx[n];
    #pragma unroll
    for (int c = 1; c < 4; ++c) {
        float v = pval[(long long)c * N_FR + n];
        int   i = pidx[(long long)c * N_FR + n];
        if (v < best) { best = v; bi = i; }   // groups ascend in index; tie keeps lower
    }
    fidx[n] = bi;
    atomicAdd(&counts[bi], 1);
}

// ------------------------------------------------------------------
// fp32 NT GEMM, bias epilogue (decoded codebook only)
// ------------------------------------------------------------------
__global__ __launch_bounds__(256)
void gemm_nt_bias(const float* __restrict__ A, const float* __restrict__ B,
                  float* __restrict__ C, int NI, int NJ, int NK,
                  const float* __restrict__ bias)
{
    const int BK = 16;
    __shared__ float As[16][128];
    __shared__ float Bs[16][128];
    const int nbi = NI / 128;
    const int bi = blockIdx.x % nbi;
    const int bj = blockIdx.x / nbi;
    const int tid = threadIdx.x;
    const int tx = tid & 15, ty = tid >> 4;
    const int i0 = bi * 128, j0 = bj * 128;
    const int r0 = tid >> 2;
    const int kq = (tid & 3) * 4;

    float acc[8][8] = {};
    for (int k0 = 0; k0 < NK; k0 += BK) {
        __syncthreads();
        #pragma unroll
        for (int rr = 0; rr < 128; rr += 64) {
            float4 va = *(const float4*)&A[(long long)(i0 + r0 + rr) * NK + k0 + kq];
            As[kq + 0][r0 + rr] = va.x; As[kq + 1][r0 + rr] = va.y;
            As[kq + 2][r0 + rr] = va.z; As[kq + 3][r0 + rr] = va.w;
            float4 vb = *(const float4*)&B[(long long)(j0 + r0 + rr) * NK + k0 + kq];
            Bs[kq + 0][r0 + rr] = vb.x; Bs[kq + 1][r0 + rr] = vb.y;
            Bs[kq + 2][r0 + rr] = vb.z; Bs[kq + 3][r0 + rr] = vb.w;
        }
        __syncthreads();
        #pragma unroll
        for (int kk = 0; kk < BK; ++kk) {
            float a[8], b[8];
            #pragma unroll
            for (int i = 0; i < 8; ++i) a[i] = As[kk][ty * 8 + i];
            #pragma unroll
            for (int j = 0; j < 8; ++j) b[j] = Bs[kk][tx * 8 + j];
            #pragma unroll
            for (int i = 0; i < 8; ++i)
                #pragma unroll
                for (int j = 0; j < 8; ++j)
                    acc[i][j] = fmaf(a[i], b[j], acc[i][j]);
        }
    }
    float bvv[8];
    #pragma unroll
    for (int j = 0; j < 8; ++j) bvv[j] = bias[j0 + tx * 8 + j];
    #pragma unroll
    for (int i = 0; i < 8; ++i) {
        int ii = i0 + ty * 8 + i;
        float4* cp = (float4*)&C[(long long)ii * NJ + j0 + tx * 8];
        cp[0] = make_float4(acc[i][0] + bvv[0], acc[i][1] + bvv[1], acc[i][2] + bvv[2], acc[i][3] + bvv[3]);
        cp[1] = make_float4(acc[i][4] + bvv[4], acc[i][5] + bvv[5], acc[i][6] + bvv[6], acc[i][7] + bvv[7]);
    }
}

__global__ __launch_bounds__(256)
void se_k(const float* __restrict__ CB, float* __restrict__ se)
{
    int row  = blockIdx.x * 4 + (threadIdx.x >> 6);
    int lane = threadIdx.x & 63;
    const float4* p = (const float4*)(CB + (long long)row * D_DIM + lane * 8);
    float4 a = p[0], b = p[1];
    float s = a.x*a.x + a.y*a.y + a.z*a.z + a.w*a.w
            + b.x*b.x + b.y*b.y + b.z*b.z + b.w*b.w;
    #pragma unroll
    for (int off = 32; off; off >>= 1) s += __shfl_xor(s, off);
    if (lane == 0) se[row] = s;
}

__global__ __launch_bounds__(256)
void loss_k(const float* __restrict__ Z, const float* __restrict__ CB,
            const int* __restrict__ fidx, double* __restrict__ dsum)
{
    int row  = blockIdx.x * 4 + (threadIdx.x >> 6);
    int lane = threadIdx.x & 63;
    int id = fidx[row];
    const float4* zp = (const float4*)(Z  + (long long)row * D_DIM + lane * 8);
    const float4* cp = (const float4*)(CB + (long long)id  * D_DIM + lane * 8);
    float4 z0 = zp[0], z1 = zp[1], c0 = cp[0], c1 = cp[1];
    float s = 0.f, d;
    d = c0.x - z0.x; s += d * d;  d = c0.y - z0.y; s += d * d;
    d = c0.z - z0.z; s += d * d;  d = c0.w - z0.w; s += d * d;
    d = c1.x - z1.x; s += d * d;  d = c1.y - z1.y; s += d * d;
    d = c1.z - z1.z; s += d * d;  d = c1.w - z1.w; s += d * d;
    #pragma unroll
    for (int off = 32; off; off >>= 1) s += __shfl_xor(s, off);
    if (lane == 0) atomicAdd(dsum, (double)s);
}

__global__ __launch_bounds__(256)
void gather_k(const float* __restrict__ DC, const int* __restrict__ fidx,
              float* __restrict__ outp)
{
    int n = blockIdx.x;
    int id = fidx[n];
    float4 v = ((const float4*)(DC + (long long)id * M_DIM))[threadIdx.x];
    ((float4*)(outp + (long long)n * M_DIM))[threadIdx.x] = v;
}

__global__ __launch_bounds__(256)
void scatter_k(const int* __restrict__ fidx, float* __restrict__ enc)
{
    int n = blockIdx.x * 256 + threadIdx.x;
    enc[(long long)n * K_CB + fidx[n]] = 1.0f;
}

__global__ __launch_bounds__(256)
void fin_k(const int* __restrict__ counts, const double* __restrict__ dsum,
           float* __restrict__ scal)
{
    __shared__ double sh[4];
    int tid = threadIdx.x;
    double s = 0.0;
    for (int k = tid; k < K_CB; k += 256) {
        double p = (double)counts[k] / (double)N_FR;
        s += p * log(p + 1e-10);
    }
    #pragma unroll
    for (int off = 32; off; off >>= 1) s += __shfl_xor(s, off);
    if ((tid & 63) == 0) sh[tid >> 6] = s;
    __syncthreads();
    if (tid == 0) {
        double tot = sh[0] + sh[1] + sh[2] + sh[3];
        scal[0] = (float)(0.25 * (*dsum) / ((double)N_FR * (double)D_DIM));
        scal[1] = (float)exp(-tot);
    }
}

extern "C" void kernel_launch(void* const* d_in, const int* in_sizes, int n_in,
                              void* d_out, int out_size, void* d_ws, size_t ws_size,
                              hipStream_t stream)
{
    (void)in_sizes; (void)n_in; (void)out_size; (void)ws_size;
    const float* x        = (const float*)d_in[0];
    const float* enc_w    = (const float*)d_in[1];
    const float* enc_b    = (const float*)d_in[2];
    const float* bn_gamma = (const float*)d_in[3];
    const float* bn_beta  = (const float*)d_in[4];
    const float* bn_mean  = (const float*)d_in[5];
    const float* bn_var   = (const float*)d_in[6];
    const float* cb       = (const float*)d_in[7];
    const float* dec_w    = (const float*)d_in[8];
    const float* dec_b    = (const float*)d_in[9];

    float* outp = (float*)d_out;
    float* z    = outp + Z_OFF;
    float* dc   = outp + DC_OFF;
    unsigned short* xh  = (unsigned short*)(outp + XH_OFF);
    unsigned short* xl  = (unsigned short*)(outp + XL_OFF);
    unsigned short* whp = (unsigned short*)(outp + WH_OFF);
    unsigned short* wlp = (unsigned short*)(outp + WL_OFF);
    unsigned short* chp = (unsigned short*)(outp + CH_OFF);
    unsigned short* clp = (unsigned short*)(outp + CL_OFF);
    unsigned short* zhp = (unsigned short*)(outp + ZH_OFF);
    unsigned short* zlp = (unsigned short*)(outp + ZL_OFF);
    float* pval = outp + PV_OFF;
    int*   pidx = (int*)(outp + PI_OFF);

    char*   wsb    = (char*)d_ws;
    int*    fidx   = (int*)wsb;                    // N ints
    int*    counts = (int*)(wsb + 131072);         // K ints
    float*  se     = (float*)(wsb + 147456);       // K floats
    double* dsum   = (double*)(wsb + 163840);      // 1 double

    hipMemsetAsync(counts, 0, 32776, stream);      // counts + se + dsum

    // split inputs into packed bf16 hi/lo
    conv_split<<<dim3(16384), 256, 0, stream>>>(x, xh, xl, M_DIM, M_DIM / 32);
    conv_split<<<dim3(256),   256, 0, stream>>>(enc_w, whp, wlp, M_DIM, M_DIM / 32);
    conv_split<<<dim3(1024),  256, 0, stream>>>(cb, chp, clp, D_DIM, D_DIM / 32);
    se_k<<<dim3(K_CB / 4), 256, 0, stream>>>(cb, se);

    // encoder (MFMA, 3-pass bf16) -> z fp32
    gemm_enc<<<dim3(1024), 256, 0, stream>>>(xh, xl, whp, wlp,
        enc_b, bn_gamma, bn_beta, bn_mean, bn_var, z);
    // split z
    conv_split<<<dim3(8192), 256, 0, stream>>>(z, zhp, zlp, D_DIM, D_DIM / 32);

    // decoded codebook (fp32): dec_cb = codebook @ dec_w.T + dec_b
    gemm_nt_bias<<<dim3((K_CB / 128) * (M_DIM / 128)), 256, 0, stream>>>(
        cb, dec_w, dc, K_CB, M_DIM, D_DIM, dec_b);

    // fused distances + argmin (grid 1024: 256 row-tiles x 4 code-groups)
    argmin_mfma<<<dim3(1024), 256, 0, stream>>>(zhp, zlp, chp, clp, se, pval, pidx);
    merge_k<<<dim3(N_FR / 256), 256, 0, stream>>>(pval, pidx, fidx, counts);

    loss_k<<<dim3(N_FR / 4), 256, 0, stream>>>(z, cb, fidx, dsum);
    gather_k<<<dim3(N_FR), 256, 0, stream>>>(dc, fidx, outp);
    fin_k<<<dim3(1), 256, 0, stream>>>(counts, dsum, outp + LOSS_OFF);

    hipMemsetAsync(outp + ENC_OFF, 0, (size_t)N_FR * K_CB * sizeof(float), stream);
    scatter_k<<<dim3(N_FR / 256), 256, 0, stream>>>(fidx, outp + ENC_OFF);
}

// Round 4
// 758.368 us; speedup vs baseline: 3.7982x; 1.5985x over previous
//
#include <hip/hip_runtime.h>
#include <math.h>
#include <float.h>

#define N_FR 32768
#define M_DIM 1024
#define D_DIM 512
#define K_CB 4096

// ---- d_out layout (floats) ----
// [0, N*M) out | [N*M] loss | [N*M+1] ppl | [N*M+2, +N*K) encodings (scratch until final)
static const long long OUT_ELEMS = (long long)N_FR * M_DIM;
static const long long LOSS_OFF  = OUT_ELEMS;
static const long long ENC_OFF   = OUT_ELEMS + 2;
static const long long Z_OFF     = ENC_OFF + 2;                         // fp32 z [N][D]
static const long long DC_OFF    = Z_OFF  + (long long)N_FR * D_DIM;    // fp32 dec_cb [K][M]
static const long long XH_OFF    = DC_OFF + (long long)K_CB * M_DIM;    // packed halves below
static const long long XL_OFF    = XH_OFF + (long long)N_FR * M_DIM / 2;
static const long long WH_OFF    = XL_OFF + (long long)N_FR * M_DIM / 2;
static const long long WL_OFF    = WH_OFF + (long long)D_DIM * M_DIM / 2;
static const long long CH_OFF    = WL_OFF + (long long)D_DIM * M_DIM / 2;
static const long long CL_OFF    = CH_OFF + (long long)K_CB * D_DIM / 2;
static const long long ZH_OFF    = CL_OFF + (long long)K_CB * D_DIM / 2;
static const long long ZL_OFF    = ZH_OFF + (long long)N_FR * D_DIM / 2;
static const long long PV_OFF    = ZL_OFF + (long long)N_FR * D_DIM / 2; // partial best val [4][N]
static const long long PI_OFF    = PV_OFF + 4LL * N_FR;                  // partial best idx [4][N]
static const long long DWH_OFF   = PI_OFF + 4LL * N_FR;                  // packed dec_w hi
static const long long DWL_OFF   = DWH_OFF + (long long)M_DIM * D_DIM / 2;
static const long long SN_OFF    = DWL_OFF + (long long)M_DIM * D_DIM / 2; // ||z_n||^2 [N]
static const long long LP_OFF    = SN_OFF + (long long)N_FR;               // loss partials [128]

typedef __attribute__((ext_vector_type(8))) short bf16x8;
typedef __attribute__((ext_vector_type(8))) unsigned short u16x8;
typedef __attribute__((ext_vector_type(4))) float f32x4;

__device__ __forceinline__ unsigned short f2bf(float f) {
    unsigned u = __float_as_uint(f);
    return (unsigned short)((u + 0x7fffu + ((u >> 16) & 1u)) >> 16);
}
__device__ __forceinline__ float bf2f(unsigned short h) {
    return __uint_as_float(((unsigned)h) << 16);
}
__device__ __forceinline__ void gl_lds16(const unsigned short* g, unsigned short* l) {
    __builtin_amdgcn_global_load_lds(
        (const __attribute__((address_space(1))) unsigned int*)g,
        (__attribute__((address_space(3))) unsigned int*)l,
        16, 0, 0);
}

// ------------------------------------------------------------------
// fp32 [R][C] -> hi/lo bf16, fragment-blocked:
// flat16 = b*512 + lane*8 + j,  b = (r>>4)*(C/32) + (c>>5),
// lane = (r&15) + 16*((c>>3)&3), j = c&7.
// ------------------------------------------------------------------
__global__ __launch_bounds__(256)
void conv_split(const float* __restrict__ in, unsigned short* __restrict__ hi,
                unsigned short* __restrict__ lo, int C, int KC)
{
    int w = blockIdx.x * 4 + (threadIdx.x >> 6);
    int lane = threadIdx.x & 63;
    int bn = w / KC, ck = w % KC;
    int r = bn * 16 + (lane & 15);
    int c = ck * 32 + (lane >> 4) * 8;
    const float4* p = (const float4*)&in[(size_t)r * C + c];
    float4 v0 = p[0], v1 = p[1];
    float f[8] = {v0.x, v0.y, v0.z, v0.w, v1.x, v1.y, v1.z, v1.w};
    u16x8 hv, lv;
    #pragma unroll
    for (int j = 0; j < 8; ++j) {
        unsigned short h = f2bf(f[j]);
        hv[j] = h;
        lv[j] = f2bf(f[j] - bf2f(h));
    }
    size_t o = (size_t)w * 512 + lane * 8;
    *(u16x8*)&hi[o] = hv;
    *(u16x8*)&lo[o] = lv;
}

// ------------------------------------------------------------------
// Packed bf16 3-pass split MFMA GEMM. 128x128 tile, 4 waves (2x2),
// wave 64x64 (4x4 frags of 16x16x32).
// EPI==0: bias+BN epilogue (encoder). EPI==1: bias only (dec codebook).
// ------------------------------------------------------------------
template<int EPI>
__global__ __launch_bounds__(256)
void gemm_pack(const unsigned short* __restrict__ ah_, const unsigned short* __restrict__ al_,
               const unsigned short* __restrict__ bh_, const unsigned short* __restrict__ bl_,
               const float* __restrict__ bias, const float* __restrict__ gamma,
               const float* __restrict__ beta, const float* __restrict__ mean,
               const float* __restrict__ var, float* __restrict__ C,
               int nbi, int nkb, int NJ)
{
    __shared__ unsigned short lds[16384];   // 32KB: ah[0:4K) al[4:8K) bh[8:12K) bl[12:16K) shorts
    const int tid = threadIdx.x, wid = tid >> 6, lane = tid & 63;
    const int wr = wid >> 1, wc = wid & 1;
    const int bi = blockIdx.x % nbi, bj = blockIdx.x / nbi;

    f32x4 acc[4][4];
    #pragma unroll
    for (int i = 0; i < 4; ++i)
        #pragma unroll
        for (int j = 0; j < 4; ++j) acc[i][j] = (f32x4){0.f, 0.f, 0.f, 0.f};

    for (int ks = 0; ks < nkb; ++ks) {
        __syncthreads();
        #pragma unroll
        for (int q = 0; q < 8; ++q) {
            int id = wid * 8 + q;
            int arr = id >> 3, rb = id & 7;
            const unsigned short* base = arr == 0 ? ah_ : arr == 1 ? al_ : arr == 2 ? bh_ : bl_;
            size_t b = (size_t)((arr < 2 ? bi : bj) * 8 + rb) * nkb + ks;
            gl_lds16(base + b * 512 + lane * 8, lds + id * 512);
        }
        __syncthreads();
        bf16x8 ah[4], al[4], bh[4], bl[4];
        #pragma unroll
        for (int i = 0; i < 4; ++i) {
            ah[i] = *(const bf16x8*)(lds + (4 * wr + i) * 512 + lane * 8);
            al[i] = *(const bf16x8*)(lds + 4096 + (4 * wr + i) * 512 + lane * 8);
        }
        #pragma unroll
        for (int j = 0; j < 4; ++j) {
            bh[j] = *(const bf16x8*)(lds + 8192  + (4 * wc + j) * 512 + lane * 8);
            bl[j] = *(const bf16x8*)(lds + 12288 + (4 * wc + j) * 512 + lane * 8);
        }
        #pragma unroll
        for (int i = 0; i < 4; ++i)
            #pragma unroll
            for (int j = 0; j < 4; ++j) {
                acc[i][j] = __builtin_amdgcn_mfma_f32_16x16x32_bf16(ah[i], bh[j], acc[i][j], 0, 0, 0);
                acc[i][j] = __builtin_amdgcn_mfma_f32_16x16x32_bf16(ah[i], bl[j], acc[i][j], 0, 0, 0);
                acc[i][j] = __builtin_amdgcn_mfma_f32_16x16x32_bf16(al[i], bh[j], acc[i][j], 0, 0, 0);
            }
    }
    #pragma unroll
    for (int j = 0; j < 4; ++j) {
        int col = bj * 128 + wc * 64 + j * 16 + (lane & 15);
        float bvv = bias[col];
        float g = 0.f, bt = 0.f, mn = 0.f, rs = 0.f;
        if (EPI == 0) {
            g  = gamma[col];
            bt = beta[col];
            mn = mean[col];
            rs = (float)(1.0 / sqrt((double)var[col] + 1e-5));
        }
        #pragma unroll
        for (int i = 0; i < 4; ++i)
            #pragma unroll
            for (int r = 0; r < 4; ++r) {
                int row = bi * 128 + wr * 64 + i * 16 + (lane >> 4) * 4 + r;
                float v = acc[i][j][r] + bvv;
                if (EPI == 0) v = (v - mn) * rs * g + bt;
                C[(size_t)row * NJ + col] = v;
            }
    }
}

// ------------------------------------------------------------------
// Fused distance + argmin. Grid 1024 = 256 row-tiles x 4 code-groups.
// Block: 128 rows x 1024 codes. Wave 64x128 (4x8 frags, 3-pass split).
// key = se[k] - 2*z.e_k ; tie -> lower index everywhere.
// ------------------------------------------------------------------
__global__ __launch_bounds__(256, 2)
void argmin_mfma(const unsigned short* __restrict__ zh, const unsigned short* __restrict__ zl,
                 const unsigned short* __restrict__ ch, const unsigned short* __restrict__ cl,
                 const float* __restrict__ se,
                 float* __restrict__ pval, int* __restrict__ pidx)
{
    __shared__ unsigned short lds[24576];   // 48KB: zh[0:8K) zl[8:16K) ch[16:32K) cl[32:48K) bytes
    __shared__ float sv[128][2];
    __shared__ int   si[128][2];
    const int tid = threadIdx.x, wid = tid >> 6, lane = tid & 63;
    const int wr = wid >> 1, wc = wid & 1;
    const int row0 = (int)(blockIdx.x >> 2) * 128;
    const int grp  = (int)(blockIdx.x & 3);

    float bv[16];
    int   bi[16];
    #pragma unroll
    for (int s = 0; s < 16; ++s) { bv[s] = FLT_MAX; bi[s] = 0x7fffffff; }

    for (int cc = 0; cc < 4; ++cc) {
        const int code0 = grp * 1024 + cc * 256;
        f32x4 acc[4][8];
        #pragma unroll
        for (int i = 0; i < 4; ++i)
            #pragma unroll
            for (int j = 0; j < 8; ++j) acc[i][j] = (f32x4){0.f, 0.f, 0.f, 0.f};

        for (int ks = 0; ks < 16; ++ks) {
            __syncthreads();
            // stage 48 x 1KB fragment-blocks: ids 0-7 zh, 8-15 zl, 16-31 ch, 32-47 cl
            #pragma unroll
            for (int q = 0; q < 12; ++q) {
                int id = wid * 12 + q;
                const unsigned short* src;
                if (id < 16) {
                    int a = id >> 3, rb = id & 7;
                    src = (a ? zl : zh) + ((size_t)((row0 >> 4) + rb) * 16 + ks) * 512 + lane * 8;
                } else {
                    int id2 = id - 16;
                    int a = id2 >> 4, cb2 = id2 & 15;
                    src = (a ? cl : ch) + ((size_t)((code0 >> 4) + cb2) * 16 + ks) * 512 + lane * 8;
                }
                gl_lds16(src, lds + id * 512);
            }
            __syncthreads();
            bf16x8 ah[4], al[4];
            #pragma unroll
            for (int i = 0; i < 4; ++i) {
                ah[i] = *(const bf16x8*)(lds + (wr * 4 + i) * 512 + lane * 8);
                al[i] = *(const bf16x8*)(lds + 4096 + (wr * 4 + i) * 512 + lane * 8);
            }
            #pragma unroll
            for (int j = 0; j < 8; ++j) {
                bf16x8 bhj = *(const bf16x8*)(lds + 8192  + (wc * 8 + j) * 512 + lane * 8);
                bf16x8 blj = *(const bf16x8*)(lds + 16384 + (wc * 8 + j) * 512 + lane * 8);
                #pragma unroll
                for (int i = 0; i < 4; ++i) {
                    acc[i][j] = __builtin_amdgcn_mfma_f32_16x16x32_bf16(ah[i], bhj, acc[i][j], 0, 0, 0);
                    acc[i][j] = __builtin_amdgcn_mfma_f32_16x16x32_bf16(ah[i], blj, acc[i][j], 0, 0, 0);
                    acc[i][j] = __builtin_amdgcn_mfma_f32_16x16x32_bf16(al[i], bhj, acc[i][j], 0, 0, 0);
                }
            }
        }
        // fold chunk into running per-lane best (codes strictly ascending)
        #pragma unroll
        for (int j = 0; j < 8; ++j) {
            int code = code0 + wc * 128 + j * 16 + (lane & 15);
            float sev = se[code];
            #pragma unroll
            for (int i = 0; i < 4; ++i)
                #pragma unroll
                for (int r = 0; r < 4; ++r) {
                    float key = sev - 2.0f * acc[i][j][r];
                    int s = i * 4 + r;
                    if (key < bv[s]) { bv[s] = key; bi[s] = code; }
                }
        }
    }
    // butterfly across the 16 code-lanes (tie -> lower index)
    #pragma unroll
    for (int s = 0; s < 16; ++s) {
        #pragma unroll
        for (int off = 1; off < 16; off <<= 1) {
            float ov = __shfl_xor(bv[s], off);
            int   oi = __shfl_xor(bi[s], off);
            if (ov < bv[s] || (ov == bv[s] && oi < bi[s])) { bv[s] = ov; bi[s] = oi; }
        }
    }
    if ((lane & 15) == 0) {
        #pragma unroll
        for (int i = 0; i < 4; ++i)
            #pragma unroll
            for (int r = 0; r < 4; ++r) {
                int row = wr * 64 + i * 16 + (lane >> 4) * 4 + r;
                sv[row][wc] = bv[i * 4 + r];
                si[row][wc] = bi[i * 4 + r];
            }
    }
    __syncthreads();
    if (tid < 128) {
        float v0 = sv[tid][0], v1 = sv[tid][1];
        int   i0 = si[tid][0], i1 = si[tid][1];
        float bvv = v0; int bii = i0;
        if (v1 < v0 || (v1 == v0 && i1 < i0)) { bvv = v1; bii = i1; }
        pval[(size_t)grp * N_FR + row0 + tid] = bvv;
        pidx[(size_t)grp * N_FR + row0 + tid] = bii;
    }
}

// ------------------------------------------------------------------
// Merge 4 code-group partials -> final index; histogram; block-reduced
// loss partial: rowloss = ||z_n||^2 + bestkey_n.
// ------------------------------------------------------------------
__global__ __launch_bounds__(256)
void merge_k(const float* __restrict__ pval, const int* __restrict__ pidx,
             const float* __restrict__ sn,
             int* __restrict__ fidx, int* __restrict__ counts,
             float* __restrict__ lpart)
{
    __shared__ float ls[4];
    int tid = threadIdx.x;
    int n = blockIdx.x * 256 + tid;
    float best = pval[n];
    int   bi   = pidx[n];
    #pragma unroll
    for (int c = 1; c < 4; ++c) {
        float v = pval[(long long)c * N_FR + n];
        int   i = pidx[(long long)c * N_FR + n];
        if (v < best) { best = v; bi = i; }   // groups ascend in index; tie keeps lower
    }
    fidx[n] = bi;
    atomicAdd(&counts[bi], 1);
    float rl = sn[n] + best;
    #pragma unroll
    for (int off = 32; off; off >>= 1) rl += __shfl_xor(rl, off);
    if ((tid & 63) == 0) ls[tid >> 6] = rl;
    __syncthreads();
    if (tid == 0) lpart[blockIdx.x] = ls[0] + ls[1] + ls[2] + ls[3];
}

// ------------------------------------------------------------------
// row-squared-norm: sn[r] = sum_d A[r][d]^2   (D_DIM columns)
// ------------------------------------------------------------------
__global__ __launch_bounds__(256)
void rownorm_k(const float* __restrict__ A, float* __restrict__ sn)
{
    int row  = blockIdx.x * 4 + (threadIdx.x >> 6);
    int lane = threadIdx.x & 63;
    const float4* p = (const float4*)(A + (long long)row * D_DIM + lane * 8);
    float4 a = p[0], b = p[1];
    float s = a.x*a.x + a.y*a.y + a.z*a.z + a.w*a.w
            + b.x*b.x + b.y*b.y + b.z*b.z + b.w*b.w;
    #pragma unroll
    for (int off = 32; off; off >>= 1) s += __shfl_xor(s, off);
    if (lane == 0) sn[row] = s;
}

// ------------------------------------------------------------------
// out[n][:] = dec_cb[idx[n]][:]
// ------------------------------------------------------------------
__global__ __launch_bounds__(256)
void gather_k(const float* __restrict__ DC, const int* __restrict__ fidx,
              float* __restrict__ outp)
{
    int n = blockIdx.x;
    int id = fidx[n];
    float4 v = ((const float4*)(DC + (long long)id * M_DIM))[threadIdx.x];
    ((float4*)(outp + (long long)n * M_DIM))[threadIdx.x] = v;
}

// ------------------------------------------------------------------
// One-pass encodings writer: zeros + one-hot, coalesced float4.
// 4 rows per block (wave per row), 16 float4 per lane.
// ------------------------------------------------------------------
__global__ __launch_bounds__(256)
void enc_write(const int* __restrict__ fidx, float* __restrict__ enc)
{
    int n    = blockIdx.x * 4 + (threadIdx.x >> 6);
    int lane = threadIdx.x & 63;
    int idx  = fidx[n];
    float4* row = (float4*)(enc + (size_t)n * K_CB);
    #pragma unroll
    for (int c = 0; c < 16; ++c) {
        int p = c * 64 + lane;
        int b4 = p * 4;
        float4 v;
        v.x = (idx == b4 + 0) ? 1.0f : 0.0f;
        v.y = (idx == b4 + 1) ? 1.0f : 0.0f;
        v.z = (idx == b4 + 2) ? 1.0f : 0.0f;
        v.w = (idx == b4 + 3) ? 1.0f : 0.0f;
        row[p] = v;
    }
}

// ------------------------------------------------------------------
// loss + perplexity scalars
// ------------------------------------------------------------------
__global__ __launch_bounds__(256)
void fin_k(const int* __restrict__ counts, const float* __restrict__ lpart,
           float* __restrict__ scal)
{
    __shared__ double sh[4], lh[4];
    int tid = threadIdx.x;
    double s = 0.0;
    for (int k = tid; k < K_CB; k += 256) {
        double p = (double)counts[k] / (double)N_FR;
        s += p * log(p + 1e-10);
    }
    double l = (tid < 128) ? (double)lpart[tid] : 0.0;
    #pragma unroll
    for (int off = 32; off; off >>= 1) {
        s += __shfl_xor(s, off);
        l += __shfl_xor(l, off);
    }
    if ((tid & 63) == 0) { sh[tid >> 6] = s; lh[tid >> 6] = l; }
    __syncthreads();
    if (tid == 0) {
        double tot = sh[0] + sh[1] + sh[2] + sh[3];
        double L   = lh[0] + lh[1] + lh[2] + lh[3];
        scal[0] = (float)(0.25 * L / ((double)N_FR * (double)D_DIM));
        scal[1] = (float)exp(-tot);
    }
}

extern "C" void kernel_launch(void* const* d_in, const int* in_sizes, int n_in,
                              void* d_out, int out_size, void* d_ws, size_t ws_size,
                              hipStream_t stream)
{
    (void)in_sizes; (void)n_in; (void)out_size; (void)ws_size;
    const float* x        = (const float*)d_in[0];
    const float* enc_w    = (const float*)d_in[1];
    const float* enc_b    = (const float*)d_in[2];
    const float* bn_gamma = (const float*)d_in[3];
    const float* bn_beta  = (const float*)d_in[4];
    const float* bn_mean  = (const float*)d_in[5];
    const float* bn_var   = (const float*)d_in[6];
    const float* cb       = (const float*)d_in[7];
    const float* dec_w    = (const float*)d_in[8];
    const float* dec_b    = (const float*)d_in[9];

    float* outp = (float*)d_out;
    float* z    = outp + Z_OFF;
    float* dc   = outp + DC_OFF;
    unsigned short* xh  = (unsigned short*)(outp + XH_OFF);
    unsigned short* xl  = (unsigned short*)(outp + XL_OFF);
    unsigned short* whp = (unsigned short*)(outp + WH_OFF);
    unsigned short* wlp = (unsigned short*)(outp + WL_OFF);
    unsigned short* chp = (unsigned short*)(outp + CH_OFF);
    unsigned short* clp = (unsigned short*)(outp + CL_OFF);
    unsigned short* zhp = (unsigned short*)(outp + ZH_OFF);
    unsigned short* zlp = (unsigned short*)(outp + ZL_OFF);
    float* pval = outp + PV_OFF;
    int*   pidx = (int*)(outp + PI_OFF);
    unsigned short* dwh = (unsigned short*)(outp + DWH_OFF);
    unsigned short* dwl = (unsigned short*)(outp + DWL_OFF);
    float* sn    = outp + SN_OFF;
    float* lpart = outp + LP_OFF;

    char*   wsb    = (char*)d_ws;
    int*    fidx   = (int*)wsb;                    // N ints
    int*    counts = (int*)(wsb + 131072);         // K ints
    float*  se     = (float*)(wsb + 147456);       // K floats

    hipMemsetAsync(counts, 0, 16384, stream);      // counts only

    // split inputs into packed bf16 hi/lo
    conv_split<<<dim3(16384), 256, 0, stream>>>(x, xh, xl, M_DIM, M_DIM / 32);
    conv_split<<<dim3(256),   256, 0, stream>>>(enc_w, whp, wlp, M_DIM, M_DIM / 32);
    conv_split<<<dim3(1024),  256, 0, stream>>>(cb, chp, clp, D_DIM, D_DIM / 32);
    conv_split<<<dim3(256),   256, 0, stream>>>(dec_w, dwh, dwl, D_DIM, D_DIM / 32);
    rownorm_k<<<dim3(K_CB / 4), 256, 0, stream>>>(cb, se);

    // encoder (MFMA, 3-pass bf16) -> z fp32
    gemm_pack<0><<<dim3(1024), 256, 0, stream>>>(xh, xl, whp, wlp,
        enc_b, bn_gamma, bn_beta, bn_mean, bn_var, z, 256, 32, D_DIM);
    // split z + row norms
    conv_split<<<dim3(8192), 256, 0, stream>>>(z, zhp, zlp, D_DIM, D_DIM / 32);
    rownorm_k<<<dim3(N_FR / 4), 256, 0, stream>>>(z, sn);

    // decoded codebook (MFMA): dec_cb = codebook @ dec_w.T + dec_b
    gemm_pack<1><<<dim3(256), 256, 0, stream>>>(chp, clp, dwh, dwl,
        dec_b, nullptr, nullptr, nullptr, nullptr, dc, 32, 16, M_DIM);

    // fused distances + argmin (grid 1024: 256 row-tiles x 4 code-groups)
    argmin_mfma<<<dim3(1024), 256, 0, stream>>>(zhp, zlp, chp, clp, se, pval, pidx);
    merge_k<<<dim3(N_FR / 256), 256, 0, stream>>>(pval, pidx, sn, fidx, counts, lpart);

    gather_k<<<dim3(N_FR), 256, 0, stream>>>(dc, fidx, outp);
    fin_k<<<dim3(1), 256, 0, stream>>>(counts, lpart, outp + LOSS_OFF);

    // final one-pass encodings write (wipes all scratch in that region)
    enc_write<<<dim3(N_FR / 4), 256, 0, stream>>>(fidx, outp + ENC_OFF);
}